// Round 15
// baseline (149.594 us; speedup 1.0000x reference)
//
#include <hip/hip_runtime.h>
#include <cstdint>
#include <cstddef>

// ---------------- types / helpers ----------------
typedef __attribute__((ext_vector_type(8)))  __bf16 bf16x8;
typedef __attribute__((ext_vector_type(4)))  float  f32x4;
typedef __attribute__((ext_vector_type(16))) float  f32x16;

#define MFMA16(a, b, c) __builtin_amdgcn_mfma_f32_16x16x32_bf16((a), (b), (c), 0, 0, 0)
#define MFMA32(a, b, c) __builtin_amdgcn_mfma_f32_32x32x16_bf16((a), (b), (c), 0, 0, 0)

#define T_SEQ 4096
#define NHEADS 8
#define DH 64
#define NROWS (2 * NHEADS * T_SEQ)   // 65536 total (bh, q) rows
#define NSPLIT 4
#define NEG_INF (-__builtin_huge_valf())
// 1/sqrt(64) * log2(e)  (softmax done in exp2 domain)
#define SCALE_Q 0.18033688011112042f

__device__ __forceinline__ unsigned short f2bf(float f) {
  unsigned int u = __float_as_uint(f);
  u += 0x7fffu + ((u >> 16) & 1u);
  return (unsigned short)(u >> 16);
}

// pack two f32 -> two bf16 in one u32 (hardware cvt_pk, RNE; lo = low half)
__device__ __forceinline__ unsigned int cvtpk(float lo, float hi) {
  unsigned int r;
  asm("v_cvt_pk_bf16_f32 %0, %1, %2" : "=v"(r) : "v"(lo), "v"(hi));
  return r;
}

// v_permlane32_swap_b32 vdst, vsrc: vdst.hi(32:63) <-> vsrc.lo(0:31)
// ((a,b) low-key-pair-first order verified on HW in R12)
__device__ __forceinline__ void swap32(unsigned int& x, unsigned int& y) {
  asm("v_permlane32_swap_b32 %0, %1" : "+v"(x), "+v"(y));
}

// pack two f32 -> two bf16 in one u32 (round-half-up; a = low half)
__device__ __forceinline__ unsigned int pack_bf2(float a, float b) {
  unsigned int au = __float_as_uint(a) + 0x8000u;
  unsigned int bu = __float_as_uint(b) + 0x8000u;
  return (au >> 16) | (bu & 0xffff0000u);
}

// async global->LDS, 16B per lane. LDS dest = uniform base + lane*16.
__device__ __forceinline__ void gload16(const unsigned short* g, unsigned short* l) {
  __builtin_amdgcn_global_load_lds(
      (const __attribute__((address_space(1))) unsigned short*)g,
      (__attribute__((address_space(3))) unsigned short*)l, 16, 0, 0);
}

// ---------------- conversion kernels ----------------
__global__ void cvt_x_kernel(const float* __restrict__ x,
                             unsigned short* __restrict__ xb, int n4) {
  int i = blockIdx.x * blockDim.x + threadIdx.x;
  if (i >= n4) return;
  float4 v = ((const float4*)x)[i];
  ushort4 o;
  o.x = f2bf(v.x); o.y = f2bf(v.y); o.z = f2bf(v.z); o.w = f2bf(v.w);
  ((ushort4*)xb)[i] = o;
}

// w [512][N] (K=512 rows) -> wT [N][512] bf16
__global__ void cvt_T_kernel(const float* __restrict__ w,
                             unsigned short* __restrict__ wT, int N, int total) {
  int i = blockIdx.x * blockDim.x + threadIdx.x;
  if (i >= total) return;
  int n = i >> 9, k = i & 511;
  wT[i] = f2bf(w[(size_t)k * N + n]);
}

// ---------------- GEMM: C = A[M,K] * BT[N,K]^T + bias ----------------
// 128x128 block tile, BK=32, 4 waves (each a 64x64 quadrant), 16x16x32 MFMA.
// m97-style staging: double-buffered LDS filled by global_load_lds dwordx4,
// prefetch of step k+1 issued before the compute of step k; ONE barrier per
// step (compiler drains vmcnt before s_barrier, publishing the tile).
// EPI==0: QKV epilogue (q/k -> [B*H][T][64], V -> transposed [B*H][64][T])
// EPI==1: fp32 output [M][512] with bias
template <int EPI>
__global__ __launch_bounds__(256) void gemm_bt(
    const unsigned short* __restrict__ A,
    const unsigned short* __restrict__ BT,
    const float* __restrict__ bias,
    float* __restrict__ outf,
    unsigned short* __restrict__ oq,
    unsigned short* __restrict__ ok,
    unsigned short* __restrict__ ovT,
    int K) {
  __shared__ alignas(16) unsigned short As[2][128 * 32];
  __shared__ alignas(16) unsigned short Bs[2][128 * 32];

  const int t = threadIdx.x;
  const int lane = t & 63;
  const int w = t >> 6;
  const int wr = (w >> 1) * 64;
  const int wc = (w & 1) * 64;
  const int g = lane >> 4, c = lane & 15;
  const int row0 = blockIdx.y * 128, col0 = blockIdx.x * 128;

  // staging map: lane covers row sr = t>>2 (64-row half per inst), 16B at
  // col (t&3)*8. LDS offset = sr*32 + (t&3)*8 = w*512 + lane*8 (linear).
  const int sr = t >> 2;
  const int sc = (t & 3) * 8;
  const unsigned short* Asrc0 = A + (size_t)(row0 + sr) * K + sc;
  const unsigned short* Asrc1 = A + (size_t)(row0 + 64 + sr) * K + sc;
  const unsigned short* Bsrc0 = BT + (size_t)(col0 + sr) * K + sc;
  const unsigned short* Bsrc1 = BT + (size_t)(col0 + 64 + sr) * K + sc;

#define STAGE_G(B, K0) do {                                    \
    gload16(Asrc0 + (K0), &As[B][w * 512]);                    \
    gload16(Asrc1 + (K0), &As[B][2048 + w * 512]);             \
    gload16(Bsrc0 + (K0), &Bs[B][w * 512]);                    \
    gload16(Bsrc1 + (K0), &Bs[B][2048 + w * 512]);             \
  } while (0)

  f32x4 acc[4][4] = {};

  STAGE_G(0, 0);
  __syncthreads();
  int cur = 0;

  for (int k0 = 0; k0 < K; k0 += 32) {
    if (k0 + 32 < K) STAGE_G(cur ^ 1, k0 + 32);

    bf16x8 af[4], bfr[4];
#pragma unroll
    for (int m = 0; m < 4; ++m)
      af[m] = *(const bf16x8*)&As[cur][(wr + m * 16 + c) * 32 + g * 8];
#pragma unroll
    for (int n = 0; n < 4; ++n)
      bfr[n] = *(const bf16x8*)&Bs[cur][(wc + n * 16 + c) * 32 + g * 8];
#pragma unroll
    for (int m = 0; m < 4; ++m)
#pragma unroll
      for (int n = 0; n < 4; ++n)
        acc[m][n] = MFMA16(af[m], bfr[n], acc[m][n]);

    __syncthreads();  // publishes prefetched tile + guards buffer reuse
    cur ^= 1;
  }
#undef STAGE_G

  // epilogue. D layout: row = g*4 + i, col = c (verified m89/m91 mapping)
#pragma unroll
  for (int m = 0; m < 4; ++m) {
#pragma unroll
    for (int n = 0; n < 4; ++n) {
      const int col = col0 + wc + n * 16 + c;
      const float bv = bias[col];
      if constexpr (EPI == 0) {
        const int which = col >> 9;          // wave-uniform (depends on block,n)
        const int h = (col >> 6) & 7;
        const int dh = col & 63;
        const int r0 = row0 + wr + m * 16 + g * 4;
        const int bb = r0 >> 12;             // r0 / T_SEQ (4 rows never cross)
        const int tt0 = r0 & 4095;
        if (which == 2) {
          // V transposed: vT[(bb*H + h)*64 + dh][tt0..tt0+3] -- contiguous
          ushort4 pk;
          pk.x = f2bf(acc[m][n][0] + bv);
          pk.y = f2bf(acc[m][n][1] + bv);
          pk.z = f2bf(acc[m][n][2] + bv);
          pk.w = f2bf(acc[m][n][3] + bv);
          *(ushort4*)&ovT[((size_t)((bb * NHEADS + h) * DH + dh)) * T_SEQ + tt0] = pk;
        } else {
          unsigned short* dst = (which == 0) ? oq : ok;
          const float sc2 = (which == 0) ? SCALE_Q : 1.0f;
#pragma unroll
          for (int i = 0; i < 4; ++i) {
            const size_t idx =
                ((size_t)((bb * NHEADS + h) * T_SEQ + tt0 + i)) * DH + dh;
            dst[idx] = f2bf((acc[m][n][i] + bv) * sc2);
          }
        }
      } else {
#pragma unroll
        for (int i = 0; i < 4; ++i) {
          const int row = row0 + wr + m * 16 + g * 4 + i;
          outf[(size_t)row * 512 + col] = acc[m][n][i] + bv;
        }
      }
    }
  }
}

// ---------------- flash attention (causal, 4-way split-K, 32x32 MFMA) -----
// grid (B*H, 16, 4). Block (bh, y, hv) runs two passes over 128-row
// q-superblocks (sb = y, 31-y), key-tile QUARTER hv of each. Per wave: 32
// q-rows via 32x32x16 MFMA, both products swapped; P stays in registers via
// cvt_pk + permlane32_swap (T12). LDS = K,V dbuf (32 KB).
// R15 micro-scheduling: V fragments hoisted BEFORE softmax (LDS || VALU
// overlap), setprio(1) around MFMA clusters (T5), launch_bounds relaxed to
// let regalloc keep S/acc in arch VGPRs (avoid accvgpr round-trips).
__global__ __launch_bounds__(256) void attn_kernel(
    const unsigned short* __restrict__ qb,
    const unsigned short* __restrict__ kb,
    const unsigned short* __restrict__ vtb,
    unsigned short* __restrict__ opart,   // NSPLIT partials, contiguous
    float* __restrict__ sb) {
  const int bh = blockIdx.x;
  const int y = blockIdx.y;
  const int hv = blockIdx.z;
  const int w = threadIdx.x >> 6;
  const int lane = threadIdx.x & 63;
  const int q32 = lane & 31;          // lane-local q row (and d row for acc)
  const int h = lane >> 5;            // half index
  const int swb = (lane & 7) << 4;    // read-side xor (bytes), row&7 == lane&7

  // K tile: rows = key (64), cols = d (64, 128B). V tile: rows = d, cols = t.
  __shared__ alignas(16) unsigned short Ks[2][64 * 64];
  __shared__ alignas(16) unsigned short Vs[2][64 * 64];

  const unsigned short* Qp  = qb + (size_t)bh * T_SEQ * DH;
  const unsigned short* Kp  = kb + (size_t)bh * T_SEQ * DH;
  const unsigned short* VTp = vtb + (size_t)bh * DH * T_SEQ;

  unsigned short* obh = opart + (size_t)hv * NROWS * DH;
  float* sbh = sb + (size_t)hv * NROWS + (size_t)bh * T_SEQ;

  // staging: wave w stages LDS rows 16w..16w+15 of both tiles (2 gloads each).
  // source column pre-swizzled: row r keeps byte-col cb at cb ^ ((r&7)<<4);
  // gload instr writes rows q*8+l8 linearly, so swizzle = 8*(lc ^ l8) elems.
  const int l8 = lane >> 3, lc = lane & 7;
  const int swzE = 8 * (lc ^ l8);
  const unsigned short* Ksrc0 = Kp + (size_t)(16 * w + l8) * DH + swzE;
  const unsigned short* Ksrc1 = Kp + (size_t)(16 * w + 8 + l8) * DH + swzE;
  const unsigned short* Vsrc0 = VTp + (size_t)(16 * w + l8) * T_SEQ + swzE;
  const unsigned short* Vsrc1 = VTp + (size_t)(16 * w + 8 + l8) * T_SEQ + swzE;

#define STAGE(B, J0) do {                                              \
    gload16(Ksrc0 + (size_t)(J0) * DH, &Ks[B][(2 * w) * 512]);         \
    gload16(Ksrc1 + (size_t)(J0) * DH, &Ks[B][(2 * w + 1) * 512]);     \
    gload16(Vsrc0 + (J0), &Vs[B][(2 * w) * 512]);                      \
    gload16(Vsrc1 + (J0), &Vs[B][(2 * w + 1) * 512]);                  \
  } while (0)

  for (int pass = 0; pass < 2; ++pass) {
    const int sbk = pass ? (31 - y) : y;      // q-superblock (128 rows)
    const int qw = sbk * 128 + w * 32;        // this wave's 32 q-rows
    const int ntp = 2 * sbk + 2;              // tiles needed by wave 3
    const int t0 = (ntp * hv) >> 2;           // quarter range [t0, t1)
    const int t1 = (ntp * (hv + 1)) >> 2;
    const int tlast = (qw + 31) >> 6;         // this wave's diagonal tile

    // Q fragments (B-operand of swapped QK): col=q=lane&31, k=16d+8h+e
    bf16x8 qf[4];
#pragma unroll
    for (int d = 0; d < 4; ++d)
      qf[d] = *(const bf16x8*)&Qp[(size_t)(qw + q32) * DH + 16 * d + 8 * h];

    f32x16 acc0 = {}, acc1 = {};
    float mi = NEG_INF;   // running row-max for q = qw + q32 (exp2 domain)
    float li = 0.f;       // running row-sum

    STAGE(0, t0 * 64);
    __syncthreads();  // compiler drains vmcnt(0) before s_barrier
    int cur = 0;

    for (int t = t0; t < t1; ++t) {
      if (t + 1 < t1) STAGE(cur ^ 1, (t + 1) * 64);

      if (t <= tlast) {  // wave-uniform; no barriers inside
        const char* Kb = (const char*)&Ks[cur][0];
        const char* Vb = (const char*)&Vs[cur][0];

        // S = K.Q^T (swapped): s{0,1}[r] = S[key=ks*32+(r&3)+8(r>>2)+4h][q]
        f32x16 s0 = {}, s1 = {};
        __builtin_amdgcn_s_setprio(1);
#pragma unroll
        for (int d = 0; d < 4; ++d) {
          bf16x8 kf0 = *(const bf16x8*)(Kb + q32 * 128 +
                                        ((32 * d + 16 * h) ^ swb));
          bf16x8 kf1 = *(const bf16x8*)(Kb + (32 + q32) * 128 +
                                        ((32 * d + 16 * h) ^ swb));
          s0 = MFMA32(kf0, qf[d], s0);
          s1 = MFMA32(kf1, qf[d], s1);
        }
        __builtin_amdgcn_s_setprio(0);

        // V fragments hoisted EARLY: 8 b128 LDS reads issue now and their
        // latency overlaps the softmax VALU chain below (ILP: LDS || VALU).
        bf16x8 vfr0[4], vfr1[4];
#pragma unroll
        for (int kk = 0; kk < 4; ++kk) {
          vfr0[kk] = *(const bf16x8*)(Vb + q32 * 128 +
                                      ((32 * kk + 16 * h) ^ swb));
          vfr1[kk] = *(const bf16x8*)(Vb + (32 + q32) * 128 +
                                      ((32 * kk + 16 * h) ^ swb));
        }

        if (t == tlast) {  // diagonal tile: causal mask (key > q)
          const int qq = qw + q32;
          const int kb0 = t * 64 + 4 * h;
#pragma unroll
          for (int r = 0; r < 16; ++r) {
            const int ko = kb0 + (r & 3) + 8 * (r >> 2);
            if (ko > qq) s0[r] = NEG_INF;
            if (ko + 32 > qq) s1[r] = NEG_INF;
          }
        }

        // row max: 31-op local tree + one cross-half shuffle
        float mv[8];
#pragma unroll
        for (int i = 0; i < 8; ++i)
          mv[i] = fmaxf(fmaxf(s0[2 * i], s0[2 * i + 1]),
                        fmaxf(s1[2 * i], s1[2 * i + 1]));
        float mloc = fmaxf(fmaxf(fmaxf(mv[0], mv[1]), fmaxf(mv[2], mv[3])),
                           fmaxf(fmaxf(mv[4], mv[5]), fmaxf(mv[6], mv[7])));
        mloc = fmaxf(mloc, __shfl_xor(mloc, 32));

        // defer-max: only rescale when some row grew past THR=8
        if (__ballot(mloc > mi + 8.0f) != 0ull) {
          const float mn = fmaxf(mi, mloc);
          const float scq = exp2f(mi - mn);
          mi = mn;
          li *= scq;
#pragma unroll
          for (int r = 0; r < 16; ++r) { acc0[r] *= scq; acc1[r] *= scq; }
        }

        // per 16-key step: exp2 -> cvt_pk -> permlane swap -> PV MFMA
        float ls = 0.f;
#pragma unroll
        for (int kk = 0; kk < 4; ++kk) {
          float pv[8];
#pragma unroll
          for (int e = 0; e < 8; ++e) {
            const float sv = (kk < 2) ? s0[(kk & 1) * 8 + e]
                                      : s1[(kk & 1) * 8 + e];
            pv[e] = exp2f(sv - mi);
          }
          ls += ((pv[0] + pv[1]) + (pv[2] + pv[3])) +
                ((pv[4] + pv[5]) + (pv[6] + pv[7]));
          // own pairs: a0=keys 4h+{0,1}, a1=4h+{2,3}, b0=8+4h+{0,1}, b1=...
          unsigned int a0 = cvtpk(pv[0], pv[1]);
          unsigned int a1 = cvtpk(pv[2], pv[3]);
          unsigned int b0 = cvtpk(pv[4], pv[5]);
          unsigned int b1 = cvtpk(pv[6], pv[7]);
          // swap32(a,b): a.hi <-> b.lo (low-key pair FIRST, HW-verified R12)
          swap32(a0, b0);
          swap32(a1, b1);
          union { unsigned int u[4]; bf16x8 v; } pf;
          pf.u[0] = a0; pf.u[1] = a1; pf.u[2] = b0; pf.u[3] = b1;

          __builtin_amdgcn_s_setprio(1);
          acc0 = MFMA32(vfr0[kk], pf.v, acc0);
          acc1 = MFMA32(vfr1[kk], pf.v, acc1);
          __builtin_amdgcn_s_setprio(0);
        }
        ls += __shfl_xor(ls, 32);
        li += ls;
      }

      // barrier: publishes prefetched tile (vmcnt drain) + buf-reuse guard
      __syncthreads();
      cur ^= 1;
    }

    // partial epilogue: o_norm (bf16) + s = mi + log2(li) per q-row.
    // acc: lane q = lane&31, d = (r&3)+8(r>>2)+4h (+32 for acc1)
    if (lane < 32) sbh[qw + lane] = (li > 0.f) ? (mi + log2f(li)) : NEG_INF;
    const float inv = (li > 0.f) ? 1.0f / li : 0.f;
    const size_t base = ((size_t)bh * T_SEQ + qw + q32) * DH;
#pragma unroll
    for (int dt = 0; dt < 2; ++dt) {
#pragma unroll
      for (int p4 = 0; p4 < 4; ++p4) {
        const float v0 = (dt ? acc1[4 * p4 + 0] : acc0[4 * p4 + 0]) * inv;
        const float v1 = (dt ? acc1[4 * p4 + 1] : acc0[4 * p4 + 1]) * inv;
        const float v2 = (dt ? acc1[4 * p4 + 2] : acc0[4 * p4 + 2]) * inv;
        const float v3 = (dt ? acc1[4 * p4 + 3] : acc0[4 * p4 + 3]) * inv;
        const int d0 = 32 * dt + 8 * p4 + 4 * h;
        *(unsigned int*)&obh[base + d0]     = cvtpk(v0, v1);
        *(unsigned int*)&obh[base + d0 + 2] = cvtpk(v2, v3);
      }
    }
  }
#undef STAGE
}

// ---------------- split-K merge (4 partials) ----------------
// y[(b*T+q)*512 + h*64 + d] = sum_i w_i * o_i, w_i = 2^(s_i - max) normalized.
// 256 threads = 32 rows x 8 dim-segments (8 bf16 = 16B each).
__global__ __launch_bounds__(256) void merge_kernel(
    const unsigned short* __restrict__ opart,
    const float* __restrict__ sb,
    unsigned short* __restrict__ yb) {
  const int t = threadIdx.x;
  const int r = blockIdx.x * 32 + (t >> 3);   // global (bh,q) row, 0..65535
  const int dseg = (t & 7) * 8;
  float s[NSPLIT];
#pragma unroll
  for (int i = 0; i < NSPLIT; ++i) s[i] = sb[(size_t)i * NROWS + r];
  const float S = fmaxf(fmaxf(s[0], s[1]), fmaxf(s[2], s[3]));
  float a[NSPLIT], wsum = 0.f;
#pragma unroll
  for (int i = 0; i < NSPLIT; ++i) { a[i] = exp2f(s[i] - S); wsum += a[i]; }
  const float inv = 1.0f / wsum;
  float acc[8] = {};
#pragma unroll
  for (int i = 0; i < NSPLIT; ++i) {
    const float ai = a[i] * inv;
    const uint4 u = *(const uint4*)&opart[(size_t)i * NROWS * DH +
                                          (size_t)r * DH + dseg];
    const unsigned int* pu = (const unsigned int*)&u;
#pragma unroll
    for (int j = 0; j < 4; ++j) {
      acc[2 * j]     += ai * __uint_as_float(pu[j] << 16);
      acc[2 * j + 1] += ai * __uint_as_float(pu[j] & 0xffff0000u);
    }
  }
  unsigned int ow[4];
#pragma unroll
  for (int j = 0; j < 4; ++j) ow[j] = pack_bf2(acc[2 * j], acc[2 * j + 1]);
  const int bh = r >> 12, q = r & 4095;
  const int bb = bh >> 3, hh = bh & 7;
  *(uint4*)&yb[((size_t)(bb * T_SEQ + q)) * 512 + hh * DH + dseg] = *(uint4*)ow;
}

// ---------------- launch ----------------
extern "C" void kernel_launch(void* const* d_in, const int* in_sizes, int n_in,
                              void* d_out, int out_size, void* d_ws, size_t ws_size,
                              hipStream_t stream) {
  const float* x     = (const float*)d_in[0];
  const float* w_qkv = (const float*)d_in[1];
  const float* b_qkv = (const float*)d_in[2];
  const float* w_out = (const float*)d_in[3];
  const float* b_out = (const float*)d_in[4];
  float* out = (float*)d_out;

  char* p = (char*)d_ws;
  unsigned short* xb    = (unsigned short*)p; p += (size_t)8192 * 512 * 2;
  unsigned short* wqkvT = (unsigned short*)p; p += (size_t)1536 * 512 * 2;
  unsigned short* woutT = (unsigned short*)p; p += (size_t)512 * 512 * 2;
  unsigned short* qbuf  = (unsigned short*)p; p += (size_t)16 * T_SEQ * DH * 2;
  unsigned short* kbuf  = (unsigned short*)p; p += (size_t)16 * T_SEQ * DH * 2;
  unsigned short* vtbuf = (unsigned short*)p; p += (size_t)16 * T_SEQ * DH * 2;
  unsigned short* ybuf  = (unsigned short*)p; p += (size_t)8192 * 512 * 2;
  unsigned short* opart = (unsigned short*)p; p += (size_t)NSPLIT * NROWS * DH * 2;
  float*          sbuf  = (float*)p;          p += (size_t)NSPLIT * NROWS * 4;

  cvt_x_kernel<<<4096, 256, 0, stream>>>(x, xb, 8192 * 512 / 4);
  cvt_T_kernel<<<3072, 256, 0, stream>>>(w_qkv, wqkvT, 1536, 1536 * 512);
  cvt_T_kernel<<<1024, 256, 0, stream>>>(w_out, woutT, 512, 512 * 512);

  // QKV projection: M=8192, N=1536, K=512
  gemm_bt<0><<<dim3(12, 64), 256, 0, stream>>>(xb, wqkvT, b_qkv, nullptr,
                                               qbuf, kbuf, vtbuf, 512);
  // attention: 128-q superblocks, paired + 4-way split-K (1024 equal blocks)
  attn_kernel<<<dim3(16, 16, NSPLIT), 256, 0, stream>>>(qbuf, kbuf, vtbuf,
                                                        opart, sbuf);
  merge_kernel<<<NROWS / 32, 256, 0, stream>>>(opart, sbuf, ybuf);
  // output projection: M=8192, N=512, K=512
  gemm_bt<1><<<dim3(4, 64), 256, 0, stream>>>(ybuf, woutT, b_out, out,
                                              nullptr, nullptr, nullptr, 512);
}

// Round 16
// 134.265 us; speedup vs baseline: 1.1142x; 1.1142x over previous
//
#include <hip/hip_runtime.h>
#include <cstdint>
#include <cstddef>

// ---------------- types / helpers ----------------
typedef __attribute__((ext_vector_type(8)))  __bf16 bf16x8;
typedef __attribute__((ext_vector_type(4)))  float  f32x4;
typedef __attribute__((ext_vector_type(16))) float  f32x16;

#define MFMA16(a, b, c) __builtin_amdgcn_mfma_f32_16x16x32_bf16((a), (b), (c), 0, 0, 0)
#define MFMA32(a, b, c) __builtin_amdgcn_mfma_f32_32x32x16_bf16((a), (b), (c), 0, 0, 0)

#define T_SEQ 4096
#define NHEADS 8
#define DH 64
#define NROWS (2 * NHEADS * T_SEQ)   // 65536 total (bh, q) rows
#define NSPLIT 4
#define NEG_INF (-__builtin_huge_valf())
// 1/sqrt(64) * log2(e)  (softmax done in exp2 domain)
#define SCALE_Q 0.18033688011112042f

__device__ __forceinline__ unsigned short f2bf(float f) {
  unsigned int u = __float_as_uint(f);
  u += 0x7fffu + ((u >> 16) & 1u);
  return (unsigned short)(u >> 16);
}

// pack two f32 -> two bf16 in one u32 (hardware cvt_pk, RNE; lo = low half)
__device__ __forceinline__ unsigned int cvtpk(float lo, float hi) {
  unsigned int r;
  asm("v_cvt_pk_bf16_f32 %0, %1, %2" : "=v"(r) : "v"(lo), "v"(hi));
  return r;
}

// v_permlane32_swap_b32 vdst, vsrc: vdst.hi(32:63) <-> vsrc.lo(0:31)
// ((a,b) low-key-pair-first order verified on HW in R12)
__device__ __forceinline__ void swap32(unsigned int& x, unsigned int& y) {
  asm("v_permlane32_swap_b32 %0, %1" : "+v"(x), "+v"(y));
}

// pack two f32 -> two bf16 in one u32 (round-half-up; a = low half)
__device__ __forceinline__ unsigned int pack_bf2(float a, float b) {
  unsigned int au = __float_as_uint(a) + 0x8000u;
  unsigned int bu = __float_as_uint(b) + 0x8000u;
  return (au >> 16) | (bu & 0xffff0000u);
}

// async global->LDS, 16B per lane. LDS dest = uniform base + lane*16.
__device__ __forceinline__ void gload16(const unsigned short* g, unsigned short* l) {
  __builtin_amdgcn_global_load_lds(
      (const __attribute__((address_space(1))) unsigned short*)g,
      (__attribute__((address_space(3))) unsigned short*)l, 16, 0, 0);
}

// ---------------- conversion kernels ----------------
__global__ void cvt_x_kernel(const float* __restrict__ x,
                             unsigned short* __restrict__ xb, int n4) {
  int i = blockIdx.x * blockDim.x + threadIdx.x;
  if (i >= n4) return;
  float4 v = ((const float4*)x)[i];
  ushort4 o;
  o.x = f2bf(v.x); o.y = f2bf(v.y); o.z = f2bf(v.z); o.w = f2bf(v.w);
  ((ushort4*)xb)[i] = o;
}

// w [512][N] (K=512 rows) -> wT [N][512] bf16
__global__ void cvt_T_kernel(const float* __restrict__ w,
                             unsigned short* __restrict__ wT, int N, int total) {
  int i = blockIdx.x * blockDim.x + threadIdx.x;
  if (i >= total) return;
  int n = i >> 9, k = i & 511;
  wT[i] = f2bf(w[(size_t)k * N + n]);
}

// ---------------- GEMM: C = A[M,K] * BT[N,K]^T + bias ----------------
// 128x128 block tile, BK=32, 4 waves (each a 64x64 quadrant), 16x16x32 MFMA.
// m97-style staging: double-buffered LDS filled by global_load_lds dwordx4,
// prefetch of step k+1 issued before the compute of step k; ONE barrier per
// step (compiler drains vmcnt before s_barrier, publishing the tile).
// EPI==0: QKV epilogue (q/k -> [B*H][T][64], V -> transposed [B*H][64][T])
// EPI==1: fp32 output [M][512] with bias
template <int EPI>
__global__ __launch_bounds__(256) void gemm_bt(
    const unsigned short* __restrict__ A,
    const unsigned short* __restrict__ BT,
    const float* __restrict__ bias,
    float* __restrict__ outf,
    unsigned short* __restrict__ oq,
    unsigned short* __restrict__ ok,
    unsigned short* __restrict__ ovT,
    int K) {
  __shared__ alignas(16) unsigned short As[2][128 * 32];
  __shared__ alignas(16) unsigned short Bs[2][128 * 32];

  const int t = threadIdx.x;
  const int lane = t & 63;
  const int w = t >> 6;
  const int wr = (w >> 1) * 64;
  const int wc = (w & 1) * 64;
  const int g = lane >> 4, c = lane & 15;
  const int row0 = blockIdx.y * 128, col0 = blockIdx.x * 128;

  // staging map: lane covers row sr = t>>2 (64-row half per inst), 16B at
  // col (t&3)*8. LDS offset = sr*32 + (t&3)*8 = w*512 + lane*8 (linear).
  const int sr = t >> 2;
  const int sc = (t & 3) * 8;
  const unsigned short* Asrc0 = A + (size_t)(row0 + sr) * K + sc;
  const unsigned short* Asrc1 = A + (size_t)(row0 + 64 + sr) * K + sc;
  const unsigned short* Bsrc0 = BT + (size_t)(col0 + sr) * K + sc;
  const unsigned short* Bsrc1 = BT + (size_t)(col0 + 64 + sr) * K + sc;

#define STAGE_G(B, K0) do {                                    \
    gload16(Asrc0 + (K0), &As[B][w * 512]);                    \
    gload16(Asrc1 + (K0), &As[B][2048 + w * 512]);             \
    gload16(Bsrc0 + (K0), &Bs[B][w * 512]);                    \
    gload16(Bsrc1 + (K0), &Bs[B][2048 + w * 512]);             \
  } while (0)

  f32x4 acc[4][4] = {};

  STAGE_G(0, 0);
  __syncthreads();
  int cur = 0;

  for (int k0 = 0; k0 < K; k0 += 32) {
    if (k0 + 32 < K) STAGE_G(cur ^ 1, k0 + 32);

    bf16x8 af[4], bfr[4];
#pragma unroll
    for (int m = 0; m < 4; ++m)
      af[m] = *(const bf16x8*)&As[cur][(wr + m * 16 + c) * 32 + g * 8];
#pragma unroll
    for (int n = 0; n < 4; ++n)
      bfr[n] = *(const bf16x8*)&Bs[cur][(wc + n * 16 + c) * 32 + g * 8];
#pragma unroll
    for (int m = 0; m < 4; ++m)
#pragma unroll
      for (int n = 0; n < 4; ++n)
        acc[m][n] = MFMA16(af[m], bfr[n], acc[m][n]);

    __syncthreads();  // publishes prefetched tile + guards buffer reuse
    cur ^= 1;
  }
#undef STAGE_G

  // epilogue. D layout: row = g*4 + i, col = c (verified m89/m91 mapping)
#pragma unroll
  for (int m = 0; m < 4; ++m) {
#pragma unroll
    for (int n = 0; n < 4; ++n) {
      const int col = col0 + wc + n * 16 + c;
      const float bv = bias[col];
      if constexpr (EPI == 0) {
        const int which = col >> 9;          // wave-uniform (depends on block,n)
        const int h = (col >> 6) & 7;
        const int dh = col & 63;
        const int r0 = row0 + wr + m * 16 + g * 4;
        const int bb = r0 >> 12;             // r0 / T_SEQ (4 rows never cross)
        const int tt0 = r0 & 4095;
        if (which == 2) {
          // V transposed: vT[(bb*H + h)*64 + dh][tt0..tt0+3] -- contiguous
          ushort4 pk;
          pk.x = f2bf(acc[m][n][0] + bv);
          pk.y = f2bf(acc[m][n][1] + bv);
          pk.z = f2bf(acc[m][n][2] + bv);
          pk.w = f2bf(acc[m][n][3] + bv);
          *(ushort4*)&ovT[((size_t)((bb * NHEADS + h) * DH + dh)) * T_SEQ + tt0] = pk;
        } else {
          unsigned short* dst = (which == 0) ? oq : ok;
          const float sc2 = (which == 0) ? SCALE_Q : 1.0f;
#pragma unroll
          for (int i = 0; i < 4; ++i) {
            const size_t idx =
                ((size_t)((bb * NHEADS + h) * T_SEQ + tt0 + i)) * DH + dh;
            dst[idx] = f2bf((acc[m][n][i] + bv) * sc2);
          }
        }
      } else {
#pragma unroll
        for (int i = 0; i < 4; ++i) {
          const int row = row0 + wr + m * 16 + g * 4 + i;
          outf[(size_t)row * 512 + col] = acc[m][n][i] + bv;
        }
      }
    }
  }
}

// ---------------- flash attention (causal, 4-way split-K, 32x32 MFMA) -----
// grid (B*H, 16, 4). Block (bh, y, hv) runs two passes over 128-row
// q-superblocks (sb = y, 31-y), key-tile QUARTER hv of each. Per wave: 32
// q-rows via 32x32x16 MFMA, both products swapped; P stays in registers via
// cvt_pk + permlane32_swap (T12). LDS = K,V dbuf (32 KB).
// R16: exact R14 structure (launch_bounds(256,4), V reads in PV loop, no
// setprio) + MFMA-li: the row-sum ls is computed by a ones-A MFMA chained
// over the 4 kk-steps (D[m][q] = sum_k P[k][q], all rows equal) instead of
// ~35 VALU adds + 1 shuffle per tile. li += z[0] once per tile. li now sums
// the same bf16-rounded P that PV consumes (self-consistent normalization).
__global__ __launch_bounds__(256, 4) void attn_kernel(
    const unsigned short* __restrict__ qb,
    const unsigned short* __restrict__ kb,
    const unsigned short* __restrict__ vtb,
    unsigned short* __restrict__ opart,   // NSPLIT partials, contiguous
    float* __restrict__ sb) {
  const int bh = blockIdx.x;
  const int y = blockIdx.y;
  const int hv = blockIdx.z;
  const int w = threadIdx.x >> 6;
  const int lane = threadIdx.x & 63;
  const int q32 = lane & 31;          // lane-local q row (and d row for acc)
  const int h = lane >> 5;            // half index
  const int swb = (lane & 7) << 4;    // read-side xor (bytes), row&7 == lane&7

  // K tile: rows = key (64), cols = d (64, 128B). V tile: rows = d, cols = t.
  __shared__ alignas(16) unsigned short Ks[2][64 * 64];
  __shared__ alignas(16) unsigned short Vs[2][64 * 64];

  const unsigned short* Qp  = qb + (size_t)bh * T_SEQ * DH;
  const unsigned short* Kp  = kb + (size_t)bh * T_SEQ * DH;
  const unsigned short* VTp = vtb + (size_t)bh * DH * T_SEQ;

  unsigned short* obh = opart + (size_t)hv * NROWS * DH;
  float* sbh = sb + (size_t)hv * NROWS + (size_t)bh * T_SEQ;

  // ones A-operand for the li MFMA (bf16 1.0 = 0x3F80)
  union { unsigned short u[8]; bf16x8 v; } ones;
#pragma unroll
  for (int i = 0; i < 8; ++i) ones.u[i] = 0x3F80;

  // staging: wave w stages LDS rows 16w..16w+15 of both tiles (2 gloads each).
  // source column pre-swizzled: row r keeps byte-col cb at cb ^ ((r&7)<<4);
  // gload instr writes rows q*8+l8 linearly, so swizzle = 8*(lc ^ l8) elems.
  const int l8 = lane >> 3, lc = lane & 7;
  const int swzE = 8 * (lc ^ l8);
  const unsigned short* Ksrc0 = Kp + (size_t)(16 * w + l8) * DH + swzE;
  const unsigned short* Ksrc1 = Kp + (size_t)(16 * w + 8 + l8) * DH + swzE;
  const unsigned short* Vsrc0 = VTp + (size_t)(16 * w + l8) * T_SEQ + swzE;
  const unsigned short* Vsrc1 = VTp + (size_t)(16 * w + 8 + l8) * T_SEQ + swzE;

#define STAGE(B, J0) do {                                              \
    gload16(Ksrc0 + (size_t)(J0) * DH, &Ks[B][(2 * w) * 512]);         \
    gload16(Ksrc1 + (size_t)(J0) * DH, &Ks[B][(2 * w + 1) * 512]);     \
    gload16(Vsrc0 + (J0), &Vs[B][(2 * w) * 512]);                      \
    gload16(Vsrc1 + (J0), &Vs[B][(2 * w + 1) * 512]);                  \
  } while (0)

  for (int pass = 0; pass < 2; ++pass) {
    const int sbk = pass ? (31 - y) : y;      // q-superblock (128 rows)
    const int qw = sbk * 128 + w * 32;        // this wave's 32 q-rows
    const int ntp = 2 * sbk + 2;              // tiles needed by wave 3
    const int t0 = (ntp * hv) >> 2;           // quarter range [t0, t1)
    const int t1 = (ntp * (hv + 1)) >> 2;
    const int tlast = (qw + 31) >> 6;         // this wave's diagonal tile

    // Q fragments (B-operand of swapped QK): col=q=lane&31, k=16d+8h+e
    bf16x8 qf[4];
#pragma unroll
    for (int d = 0; d < 4; ++d)
      qf[d] = *(const bf16x8*)&Qp[(size_t)(qw + q32) * DH + 16 * d + 8 * h];

    f32x16 acc0 = {}, acc1 = {};
    float mi = NEG_INF;   // running row-max for q = qw + q32 (exp2 domain)
    float li = 0.f;       // running row-sum

    STAGE(0, t0 * 64);
    __syncthreads();  // compiler drains vmcnt(0) before s_barrier
    int cur = 0;

    for (int t = t0; t < t1; ++t) {
      if (t + 1 < t1) STAGE(cur ^ 1, (t + 1) * 64);

      if (t <= tlast) {  // wave-uniform; no barriers inside
        const char* Kb = (const char*)&Ks[cur][0];
        const char* Vb = (const char*)&Vs[cur][0];

        // S = K.Q^T (swapped): s{0,1}[r] = S[key=ks*32+(r&3)+8(r>>2)+4h][q]
        f32x16 s0 = {}, s1 = {};
#pragma unroll
        for (int d = 0; d < 4; ++d) {
          bf16x8 kf0 = *(const bf16x8*)(Kb + q32 * 128 +
                                        ((32 * d + 16 * h) ^ swb));
          bf16x8 kf1 = *(const bf16x8*)(Kb + (32 + q32) * 128 +
                                        ((32 * d + 16 * h) ^ swb));
          s0 = MFMA32(kf0, qf[d], s0);
          s1 = MFMA32(kf1, qf[d], s1);
        }

        if (t == tlast) {  // diagonal tile: causal mask (key > q)
          const int qq = qw + q32;
          const int kb0 = t * 64 + 4 * h;
#pragma unroll
          for (int r = 0; r < 16; ++r) {
            const int ko = kb0 + (r & 3) + 8 * (r >> 2);
            if (ko > qq) s0[r] = NEG_INF;
            if (ko + 32 > qq) s1[r] = NEG_INF;
          }
        }

        // row max: 31-op local tree + one cross-half shuffle
        float mv[8];
#pragma unroll
        for (int i = 0; i < 8; ++i)
          mv[i] = fmaxf(fmaxf(s0[2 * i], s0[2 * i + 1]),
                        fmaxf(s1[2 * i], s1[2 * i + 1]));
        float mloc = fmaxf(fmaxf(fmaxf(mv[0], mv[1]), fmaxf(mv[2], mv[3])),
                           fmaxf(fmaxf(mv[4], mv[5]), fmaxf(mv[6], mv[7])));
        mloc = fmaxf(mloc, __shfl_xor(mloc, 32));

        // defer-max: only rescale when some row grew past THR=8
        if (__ballot(mloc > mi + 8.0f) != 0ull) {
          const float mn = fmaxf(mi, mloc);
          const float scq = exp2f(mi - mn);
          mi = mn;
          li *= scq;
#pragma unroll
          for (int r = 0; r < 16; ++r) { acc0[r] *= scq; acc1[r] *= scq; }
        }

        // per 16-key step: exp2 -> cvt_pk -> permlane swap -> PV MFMA.
        // z accumulates the P column-sums on the MFMA pipe (ones-A).
        f32x16 z = {};
#pragma unroll
        for (int kk = 0; kk < 4; ++kk) {
          float pv[8];
#pragma unroll
          for (int e = 0; e < 8; ++e) {
            const float sv = (kk < 2) ? s0[(kk & 1) * 8 + e]
                                      : s1[(kk & 1) * 8 + e];
            pv[e] = exp2f(sv - mi);
          }
          // own pairs: a0=keys 4h+{0,1}, a1=4h+{2,3}, b0=8+4h+{0,1}, b1=...
          unsigned int a0 = cvtpk(pv[0], pv[1]);
          unsigned int a1 = cvtpk(pv[2], pv[3]);
          unsigned int b0 = cvtpk(pv[4], pv[5]);
          unsigned int b1 = cvtpk(pv[6], pv[7]);
          // swap32(a,b): a.hi <-> b.lo (low-key pair FIRST, HW-verified R12)
          swap32(a0, b0);
          swap32(a1, b1);
          union { unsigned int u[4]; bf16x8 v; } pf;
          pf.u[0] = a0; pf.u[1] = a1; pf.u[2] = b0; pf.u[3] = b1;

          bf16x8 vf0 = *(const bf16x8*)(Vb + q32 * 128 +
                                        ((32 * kk + 16 * h) ^ swb));
          bf16x8 vf1 = *(const bf16x8*)(Vb + (32 + q32) * 128 +
                                        ((32 * kk + 16 * h) ^ swb));
          acc0 = MFMA32(vf0, pf.v, acc0);
          acc1 = MFMA32(vf1, pf.v, acc1);
          z = MFMA32(ones.v, pf.v, z);   // row-sum on the matrix pipe
        }
        li += z[0];   // all rows of z are equal; z[0] = sum over 64 keys
      }

      // barrier: publishes prefetched tile (vmcnt drain) + buf-reuse guard
      __syncthreads();
      cur ^= 1;
    }

    // partial epilogue: o_norm (bf16) + s = mi + log2(li) per q-row.
    // acc: lane q = lane&31, d = (r&3)+8(r>>2)+4h (+32 for acc1)
    if (lane < 32) sbh[qw + lane] = (li > 0.f) ? (mi + log2f(li)) : NEG_INF;
    const float inv = (li > 0.f) ? 1.0f / li : 0.f;
    const size_t base = ((size_t)bh * T_SEQ + qw + q32) * DH;
#pragma unroll
    for (int dt = 0; dt < 2; ++dt) {
#pragma unroll
      for (int p4 = 0; p4 < 4; ++p4) {
        const float v0 = (dt ? acc1[4 * p4 + 0] : acc0[4 * p4 + 0]) * inv;
        const float v1 = (dt ? acc1[4 * p4 + 1] : acc0[4 * p4 + 1]) * inv;
        const float v2 = (dt ? acc1[4 * p4 + 2] : acc0[4 * p4 + 2]) * inv;
        const float v3 = (dt ? acc1[4 * p4 + 3] : acc0[4 * p4 + 3]) * inv;
        const int d0 = 32 * dt + 8 * p4 + 4 * h;
        *(unsigned int*)&obh[base + d0]     = cvtpk(v0, v1);
        *(unsigned int*)&obh[base + d0 + 2] = cvtpk(v2, v3);
      }
    }
  }
#undef STAGE
}

// ---------------- split-K merge (4 partials) ----------------
// y[(b*T+q)*512 + h*64 + d] = sum_i w_i * o_i, w_i = 2^(s_i - max) normalized.
// 256 threads = 32 rows x 8 dim-segments (8 bf16 = 16B each).
__global__ __launch_bounds__(256) void merge_kernel(
    const unsigned short* __restrict__ opart,
    const float* __restrict__ sb,
    unsigned short* __restrict__ yb) {
  const int t = threadIdx.x;
  const int r = blockIdx.x * 32 + (t >> 3);   // global (bh,q) row, 0..65535
  const int dseg = (t & 7) * 8;
  float s[NSPLIT];
#pragma unroll
  for (int i = 0; i < NSPLIT; ++i) s[i] = sb[(size_t)i * NROWS + r];
  const float S = fmaxf(fmaxf(s[0], s[1]), fmaxf(s[2], s[3]));
  float a[NSPLIT], wsum = 0.f;
#pragma unroll
  for (int i = 0; i < NSPLIT; ++i) { a[i] = exp2f(s[i] - S); wsum += a[i]; }
  const float inv = 1.0f / wsum;
  float acc[8] = {};
#pragma unroll
  for (int i = 0; i < NSPLIT; ++i) {
    const float ai = a[i] * inv;
    const uint4 u = *(const uint4*)&opart[(size_t)i * NROWS * DH +
                                          (size_t)r * DH + dseg];
    const unsigned int* pu = (const unsigned int*)&u;
#pragma unroll
    for (int j = 0; j < 4; ++j) {
      acc[2 * j]     += ai * __uint_as_float(pu[j] << 16);
      acc[2 * j + 1] += ai * __uint_as_float(pu[j] & 0xffff0000u);
    }
  }
  unsigned int ow[4];
#pragma unroll
  for (int j = 0; j < 4; ++j) ow[j] = pack_bf2(acc[2 * j], acc[2 * j + 1]);
  const int bh = r >> 12, q = r & 4095;
  const int bb = bh >> 3, hh = bh & 7;
  *(uint4*)&yb[((size_t)(bb * T_SEQ + q)) * 512 + hh * DH + dseg] = *(uint4*)ow;
}

// ---------------- launch ----------------
extern "C" void kernel_launch(void* const* d_in, const int* in_sizes, int n_in,
                              void* d_out, int out_size, void* d_ws, size_t ws_size,
                              hipStream_t stream) {
  const float* x     = (const float*)d_in[0];
  const float* w_qkv = (const float*)d_in[1];
  const float* b_qkv = (const float*)d_in[2];
  const float* w_out = (const float*)d_in[3];
  const float* b_out = (const float*)d_in[4];
  float* out = (float*)d_out;

  char* p = (char*)d_ws;
  unsigned short* xb    = (unsigned short*)p; p += (size_t)8192 * 512 * 2;
  unsigned short* wqkvT = (unsigned short*)p; p += (size_t)1536 * 512 * 2;
  unsigned short* woutT = (unsigned short*)p; p += (size_t)512 * 512 * 2;
  unsigned short* qbuf  = (unsigned short*)p; p += (size_t)16 * T_SEQ * DH * 2;
  unsigned short* kbuf  = (unsigned short*)p; p += (size_t)16 * T_SEQ * DH * 2;
  unsigned short* vtbuf = (unsigned short*)p; p += (size_t)16 * T_SEQ * DH * 2;
  unsigned short* ybuf  = (unsigned short*)p; p += (size_t)8192 * 512 * 2;
  unsigned short* opart = (unsigned short*)p; p += (size_t)NSPLIT * NROWS * DH * 2;
  float*          sbuf  = (float*)p;          p += (size_t)NSPLIT * NROWS * 4;

  cvt_x_kernel<<<4096, 256, 0, stream>>>(x, xb, 8192 * 512 / 4);
  cvt_T_kernel<<<3072, 256, 0, stream>>>(w_qkv, wqkvT, 1536, 1536 * 512);
  cvt_T_kernel<<<1024, 256, 0, stream>>>(w_out, woutT, 512, 512 * 512);

  // QKV projection: M=8192, N=1536, K=512
  gemm_bt<0><<<dim3(12, 64), 256, 0, stream>>>(xb, wqkvT, b_qkv, nullptr,
                                               qbuf, kbuf, vtbuf, 512);
  // attention: 128-q superblocks, paired + 4-way split-K (1024 equal blocks)
  attn_kernel<<<dim3(16, 16, NSPLIT), 256, 0, stream>>>(qbuf, kbuf, vtbuf,
                                                        opart, sbuf);
  merge_kernel<<<NROWS / 32, 256, 0, stream>>>(opart, sbuf, ybuf);
  // output projection: M=8192, N=512, K=512
  gemm_bt<1><<<dim3(4, 64), 256, 0, stream>>>(ybuf, woutT, b_out, out,
                                              nullptr, nullptr, nullptr, 512);
}

// Round 18
// 126.935 us; speedup vs baseline: 1.1785x; 1.0577x over previous
//
#include <hip/hip_runtime.h>
#include <cstdint>
#include <cstddef>

// ---------------- types / helpers ----------------
typedef __attribute__((ext_vector_type(8)))  __bf16 bf16x8;
typedef __attribute__((ext_vector_type(4)))  float  f32x4;
typedef __attribute__((ext_vector_type(16))) float  f32x16;

#define MFMA16(a, b, c) __builtin_amdgcn_mfma_f32_16x16x32_bf16((a), (b), (c), 0, 0, 0)
#define MFMA32(a, b, c) __builtin_amdgcn_mfma_f32_32x32x16_bf16((a), (b), (c), 0, 0, 0)

#define T_SEQ 4096
#define NHEADS 8
#define DH 64
#define NROWS (2 * NHEADS * T_SEQ)   // 65536 total (bh, q) rows
#define NSPLIT 4
#define NEG_INF (-__builtin_huge_valf())
// 1/sqrt(64) * log2(e)  (softmax done in exp2 domain)
#define SCALE_Q 0.18033688011112042f

__device__ __forceinline__ unsigned short f2bf(float f) {
  unsigned int u = __float_as_uint(f);
  u += 0x7fffu + ((u >> 16) & 1u);
  return (unsigned short)(u >> 16);
}

// pack two f32 -> two bf16 in one u32 (hardware cvt_pk, RNE; lo = low half)
__device__ __forceinline__ unsigned int cvtpk(float lo, float hi) {
  unsigned int r;
  asm("v_cvt_pk_bf16_f32 %0, %1, %2" : "=v"(r) : "v"(lo), "v"(hi));
  return r;
}

// v_permlane32_swap_b32 vdst, vsrc: vdst.hi(32:63) <-> vsrc.lo(0:31)
// ((a,b) low-key-pair-first order verified on HW in R12)
__device__ __forceinline__ void swap32(unsigned int& x, unsigned int& y) {
  asm("v_permlane32_swap_b32 %0, %1" : "+v"(x), "+v"(y));
}

// pack two f32 -> two bf16 in one u32 (round-half-up; a = low half)
__device__ __forceinline__ unsigned int pack_bf2(float a, float b) {
  unsigned int au = __float_as_uint(a) + 0x8000u;
  unsigned int bu = __float_as_uint(b) + 0x8000u;
  return (au >> 16) | (bu & 0xffff0000u);
}

// async global->LDS, 16B per lane. LDS dest = uniform base + lane*16.
__device__ __forceinline__ void gload16(const unsigned short* g, unsigned short* l) {
  __builtin_amdgcn_global_load_lds(
      (const __attribute__((address_space(1))) unsigned short*)g,
      (__attribute__((address_space(3))) unsigned short*)l, 16, 0, 0);
}

// ---------------- fused conversion kernel ----------------
// blocks [0,4096): x -> bf16 (4 elems/thread); [4096,7168): w_qkv^T;
// [7168,8192): w_out^T. Exact coverage, no guards.
__global__ __launch_bounds__(256) void cvt_all_kernel(
    const float* __restrict__ x,
    const float* __restrict__ w_qkv,
    const float* __restrict__ w_out,
    unsigned short* __restrict__ xb,
    unsigned short* __restrict__ wqkvT,
    unsigned short* __restrict__ woutT) {
  const int b = blockIdx.x;
  if (b < 4096) {
    const int i = b * 256 + threadIdx.x;          // 4096*256*4 = 8192*512
    float4 v = ((const float4*)x)[i];
    ushort4 o;
    o.x = f2bf(v.x); o.y = f2bf(v.y); o.z = f2bf(v.z); o.w = f2bf(v.w);
    ((ushort4*)xb)[i] = o;
  } else if (b < 7168) {
    const int i = (b - 4096) * 256 + threadIdx.x; // 1536*512
    const int n = i >> 9, k = i & 511;
    wqkvT[i] = f2bf(w_qkv[(size_t)k * 1536 + n]);
  } else {
    const int i = (b - 7168) * 256 + threadIdx.x; // 512*512
    const int n = i >> 9, k = i & 511;
    woutT[i] = f2bf(w_out[(size_t)k * 512 + n]);
  }
}

// ---------------- QKV GEMM: C = A[M,K] * BT[N,K]^T + bias ----------------
// 128x128 block tile, BK=32, 4 waves (each a 64x64 quadrant), 16x16x32 MFMA.
// m97-style staging: double-buffered LDS filled by global_load_lds dwordx4,
// prefetch of step k+1 issued before compute of step k; one barrier/step.
// Epilogue: q/k -> [B*H][T][64], V -> transposed [B*H][64][T].
__global__ __launch_bounds__(256) void gemm_qkv(
    const unsigned short* __restrict__ A,
    const unsigned short* __restrict__ BT,
    const float* __restrict__ bias,
    unsigned short* __restrict__ oq,
    unsigned short* __restrict__ ok,
    unsigned short* __restrict__ ovT,
    int K) {
  __shared__ alignas(16) unsigned short As[2][128 * 32];
  __shared__ alignas(16) unsigned short Bs[2][128 * 32];

  const int t = threadIdx.x;
  const int lane = t & 63;
  const int w = t >> 6;
  const int wr = (w >> 1) * 64;
  const int wc = (w & 1) * 64;
  const int g = lane >> 4, c = lane & 15;
  const int row0 = blockIdx.y * 128, col0 = blockIdx.x * 128;

  // staging map: lane covers row sr = t>>2, 16B at col (t&3)*8. Linear LDS.
  const int sr = t >> 2;
  const int sc = (t & 3) * 8;
  const unsigned short* Asrc0 = A + (size_t)(row0 + sr) * K + sc;
  const unsigned short* Asrc1 = A + (size_t)(row0 + 64 + sr) * K + sc;
  const unsigned short* Bsrc0 = BT + (size_t)(col0 + sr) * K + sc;
  const unsigned short* Bsrc1 = BT + (size_t)(col0 + 64 + sr) * K + sc;

#define STAGE_G(B, K0) do {                                    \
    gload16(Asrc0 + (K0), &As[B][w * 512]);                    \
    gload16(Asrc1 + (K0), &As[B][2048 + w * 512]);             \
    gload16(Bsrc0 + (K0), &Bs[B][w * 512]);                    \
    gload16(Bsrc1 + (K0), &Bs[B][2048 + w * 512]);             \
  } while (0)

  f32x4 acc[4][4] = {};

  STAGE_G(0, 0);
  __syncthreads();
  int cur = 0;

  for (int k0 = 0; k0 < K; k0 += 32) {
    if (k0 + 32 < K) STAGE_G(cur ^ 1, k0 + 32);

    bf16x8 af[4], bfr[4];
#pragma unroll
    for (int m = 0; m < 4; ++m)
      af[m] = *(const bf16x8*)&As[cur][(wr + m * 16 + c) * 32 + g * 8];
#pragma unroll
    for (int n = 0; n < 4; ++n)
      bfr[n] = *(const bf16x8*)&Bs[cur][(wc + n * 16 + c) * 32 + g * 8];
#pragma unroll
    for (int m = 0; m < 4; ++m)
#pragma unroll
      for (int n = 0; n < 4; ++n)
        acc[m][n] = MFMA16(af[m], bfr[n], acc[m][n]);

    __syncthreads();  // publishes prefetched tile + guards buffer reuse
    cur ^= 1;
  }
#undef STAGE_G

  // epilogue. D layout: row = g*4 + i, col = c (verified m89/m91 mapping)
#pragma unroll
  for (int m = 0; m < 4; ++m) {
#pragma unroll
    for (int n = 0; n < 4; ++n) {
      const int col = col0 + wc + n * 16 + c;
      const float bv = bias[col];
      const int which = col >> 9;          // wave-uniform (depends on block,n)
      const int h = (col >> 6) & 7;
      const int dh = col & 63;
      const int r0 = row0 + wr + m * 16 + g * 4;
      const int bb = r0 >> 12;             // r0 / T_SEQ (4 rows never cross)
      const int tt0 = r0 & 4095;
      if (which == 2) {
        // V transposed: vT[(bb*H + h)*64 + dh][tt0..tt0+3] -- contiguous
        ushort4 pk;
        pk.x = f2bf(acc[m][n][0] + bv);
        pk.y = f2bf(acc[m][n][1] + bv);
        pk.z = f2bf(acc[m][n][2] + bv);
        pk.w = f2bf(acc[m][n][3] + bv);
        *(ushort4*)&ovT[((size_t)((bb * NHEADS + h) * DH + dh)) * T_SEQ + tt0] = pk;
      } else {
        unsigned short* dst = (which == 0) ? oq : ok;
        const float sc2 = (which == 0) ? SCALE_Q : 1.0f;
#pragma unroll
        for (int i = 0; i < 4; ++i) {
          const size_t idx =
              ((size_t)((bb * NHEADS + h) * T_SEQ + tt0 + i)) * DH + dh;
          dst[idx] = f2bf((acc[m][n][i] + bv) * sc2);
        }
      }
    }
  }
}

// ---------------- out-proj GEMM: 64x128 tile (high-occupancy) ----------
// M=8192, N=512, K=512. Tile 64 rows x 128 cols -> grid (4,128) = 512
// blocks = 2 blocks/CU (vs 1/CU with 128x128 -- the R16 bottleneck).
// 4 waves: each 32x64 quadrant (acc[2][4]). A staging = 1 gload/buffer
// (64x32), B = 2. LDS 24 KB. fp32 output with bias.
__global__ __launch_bounds__(256) void gemm_out(
    const unsigned short* __restrict__ A,
    const unsigned short* __restrict__ BT,
    const float* __restrict__ bias,
    float* __restrict__ outf,
    int K) {
  __shared__ alignas(16) unsigned short As[2][64 * 32];
  __shared__ alignas(16) unsigned short Bs[2][128 * 32];

  const int t = threadIdx.x;
  const int lane = t & 63;
  const int w = t >> 6;
  const int wr = (w >> 1) * 32;
  const int wc = (w & 1) * 64;
  const int g = lane >> 4, c = lane & 15;
  const int row0 = blockIdx.y * 64, col0 = blockIdx.x * 128;

  const int sr = t >> 2;            // 0..63
  const int sc = (t & 3) * 8;
  const unsigned short* Asrc  = A + (size_t)(row0 + sr) * K + sc;
  const unsigned short* Bsrc0 = BT + (size_t)(col0 + sr) * K + sc;
  const unsigned short* Bsrc1 = BT + (size_t)(col0 + 64 + sr) * K + sc;

#define STAGE_O(B, K0) do {                                    \
    gload16(Asrc + (K0), &As[B][w * 512]);                     \
    gload16(Bsrc0 + (K0), &Bs[B][w * 512]);                    \
    gload16(Bsrc1 + (K0), &Bs[B][2048 + w * 512]);             \
  } while (0)

  f32x4 acc[2][4] = {};

  STAGE_O(0, 0);
  __syncthreads();
  int cur = 0;

  for (int k0 = 0; k0 < K; k0 += 32) {
    if (k0 + 32 < K) STAGE_O(cur ^ 1, k0 + 32);

    bf16x8 af[2], bfr[4];
#pragma unroll
    for (int m = 0; m < 2; ++m)
      af[m] = *(const bf16x8*)&As[cur][(wr + m * 16 + c) * 32 + g * 8];
#pragma unroll
    for (int n = 0; n < 4; ++n)
      bfr[n] = *(const bf16x8*)&Bs[cur][(wc + n * 16 + c) * 32 + g * 8];
#pragma unroll
    for (int m = 0; m < 2; ++m)
#pragma unroll
      for (int n = 0; n < 4; ++n)
        acc[m][n] = MFMA16(af[m], bfr[n], acc[m][n]);

    __syncthreads();
    cur ^= 1;
  }
#undef STAGE_O

#pragma unroll
  for (int m = 0; m < 2; ++m) {
#pragma unroll
    for (int n = 0; n < 4; ++n) {
      const int col = col0 + wc + n * 16 + c;
      const float bv = bias[col];
#pragma unroll
      for (int i = 0; i < 4; ++i) {
        const int row = row0 + wr + m * 16 + g * 4 + i;
        outf[(size_t)row * 512 + col] = acc[m][n][i] + bv;
      }
    }
  }
}

// ---------------- flash attention (causal, 4-way split-K, 32x32 MFMA) -----
// grid (B*H, 16, 4). Block (bh, y, hv) runs two passes over 128-row
// q-superblocks (sb = y, 31-y), key-tile QUARTER hv of each. Per wave: 32
// q-rows via 32x32x16 MFMA, both products swapped; P stays in registers via
// cvt_pk + permlane32_swap (T12). LDS = K,V dbuf (32 KB). MFMA-li: row-sum
// via ones-A MFMA (z), li += z[0]. (R16 config -- best measured, 79.3 us.)
__global__ __launch_bounds__(256, 4) void attn_kernel(
    const unsigned short* __restrict__ qb,
    const unsigned short* __restrict__ kb,
    const unsigned short* __restrict__ vtb,
    unsigned short* __restrict__ opart,   // NSPLIT partials, contiguous
    float* __restrict__ sb) {
  const int bh = blockIdx.x;
  const int y = blockIdx.y;
  const int hv = blockIdx.z;
  const int w = threadIdx.x >> 6;
  const int lane = threadIdx.x & 63;
  const int q32 = lane & 31;          // lane-local q row (and d row for acc)
  const int h = lane >> 5;            // half index
  const int swb = (lane & 7) << 4;    // read-side xor (bytes), row&7 == lane&7

  // K tile: rows = key (64), cols = d (64, 128B). V tile: rows = d, cols = t.
  __shared__ alignas(16) unsigned short Ks[2][64 * 64];
  __shared__ alignas(16) unsigned short Vs[2][64 * 64];

  const unsigned short* Qp  = qb + (size_t)bh * T_SEQ * DH;
  const unsigned short* Kp  = kb + (size_t)bh * T_SEQ * DH;
  const unsigned short* VTp = vtb + (size_t)bh * DH * T_SEQ;

  unsigned short* obh = opart + (size_t)hv * NROWS * DH;
  float* sbh = sb + (size_t)hv * NROWS + (size_t)bh * T_SEQ;

  // ones A-operand for the li MFMA (bf16 1.0 = 0x3F80)
  union { unsigned short u[8]; bf16x8 v; } ones;
#pragma unroll
  for (int i = 0; i < 8; ++i) ones.u[i] = 0x3F80;

  // staging: wave w stages LDS rows 16w..16w+15 of both tiles (2 gloads each).
  // source column pre-swizzled: row r keeps byte-col cb at cb ^ ((r&7)<<4);
  // gload instr writes rows q*8+l8 linearly, so swizzle = 8*(lc ^ l8) elems.
  const int l8 = lane >> 3, lc = lane & 7;
  const int swzE = 8 * (lc ^ l8);
  const unsigned short* Ksrc0 = Kp + (size_t)(16 * w + l8) * DH + swzE;
  const unsigned short* Ksrc1 = Kp + (size_t)(16 * w + 8 + l8) * DH + swzE;
  const unsigned short* Vsrc0 = VTp + (size_t)(16 * w + l8) * T_SEQ + swzE;
  const unsigned short* Vsrc1 = VTp + (size_t)(16 * w + 8 + l8) * T_SEQ + swzE;

#define STAGE(B, J0) do {                                              \
    gload16(Ksrc0 + (size_t)(J0) * DH, &Ks[B][(2 * w) * 512]);         \
    gload16(Ksrc1 + (size_t)(J0) * DH, &Ks[B][(2 * w + 1) * 512]);     \
    gload16(Vsrc0 + (J0), &Vs[B][(2 * w) * 512]);                      \
    gload16(Vsrc1 + (J0), &Vs[B][(2 * w + 1) * 512]);                  \
  } while (0)

  for (int pass = 0; pass < 2; ++pass) {
    const int sbk = pass ? (31 - y) : y;      // q-superblock (128 rows)
    const int qw = sbk * 128 + w * 32;        // this wave's 32 q-rows
    const int ntp = 2 * sbk + 2;              // tiles needed by wave 3
    const int t0 = (ntp * hv) >> 2;           // quarter range [t0, t1)
    const int t1 = (ntp * (hv + 1)) >> 2;
    const int tlast = (qw + 31) >> 6;         // this wave's diagonal tile

    // Q fragments (B-operand of swapped QK): col=q=lane&31, k=16d+8h+e
    bf16x8 qf[4];
#pragma unroll
    for (int d = 0; d < 4; ++d)
      qf[d] = *(const bf16x8*)&Qp[(size_t)(qw + q32) * DH + 16 * d + 8 * h];

    f32x16 acc0 = {}, acc1 = {};
    float mi = NEG_INF;   // running row-max for q = qw + q32 (exp2 domain)
    float li = 0.f;       // running row-sum

    STAGE(0, t0 * 64);
    __syncthreads();  // compiler drains vmcnt(0) before s_barrier
    int cur = 0;

    for (int t = t0; t < t1; ++t) {
      if (t + 1 < t1) STAGE(cur ^ 1, (t + 1) * 64);

      if (t <= tlast) {  // wave-uniform; no barriers inside
        const char* Kb = (const char*)&Ks[cur][0];
        const char* Vb = (const char*)&Vs[cur][0];

        // S = K.Q^T (swapped): s{0,1}[r] = S[key=ks*32+(r&3)+8(r>>2)+4h][q]
        f32x16 s0 = {}, s1 = {};
#pragma unroll
        for (int d = 0; d < 4; ++d) {
          bf16x8 kf0 = *(const bf16x8*)(Kb + q32 * 128 +
                                        ((32 * d + 16 * h) ^ swb));
          bf16x8 kf1 = *(const bf16x8*)(Kb + (32 + q32) * 128 +
                                        ((32 * d + 16 * h) ^ swb));
          s0 = MFMA32(kf0, qf[d], s0);
          s1 = MFMA32(kf1, qf[d], s1);
        }

        if (t == tlast) {  // diagonal tile: causal mask (key > q)
          const int qq = qw + q32;
          const int kb0 = t * 64 + 4 * h;
#pragma unroll
          for (int r = 0; r < 16; ++r) {
            const int ko = kb0 + (r & 3) + 8 * (r >> 2);
            if (ko > qq) s0[r] = NEG_INF;
            if (ko + 32 > qq) s1[r] = NEG_INF;
          }
        }

        // row max: 31-op local tree + one cross-half shuffle
        float mv[8];
#pragma unroll
        for (int i = 0; i < 8; ++i)
          mv[i] = fmaxf(fmaxf(s0[2 * i], s0[2 * i + 1]),
                        fmaxf(s1[2 * i], s1[2 * i + 1]));
        float mloc = fmaxf(fmaxf(fmaxf(mv[0], mv[1]), fmaxf(mv[2], mv[3])),
                           fmaxf(fmaxf(mv[4], mv[5]), fmaxf(mv[6], mv[7])));
        mloc = fmaxf(mloc, __shfl_xor(mloc, 32));

        // defer-max: only rescale when some row grew past THR=8
        if (__ballot(mloc > mi + 8.0f) != 0ull) {
          const float mn = fmaxf(mi, mloc);
          const float scq = exp2f(mi - mn);
          mi = mn;
          li *= scq;
#pragma unroll
          for (int r = 0; r < 16; ++r) { acc0[r] *= scq; acc1[r] *= scq; }
        }

        // per 16-key step: exp2 -> cvt_pk -> permlane swap -> PV MFMA.
        // z accumulates the P column-sums on the MFMA pipe (ones-A).
        f32x16 z = {};
#pragma unroll
        for (int kk = 0; kk < 4; ++kk) {
          float pv[8];
#pragma unroll
          for (int e = 0; e < 8; ++e) {
            const float sv = (kk < 2) ? s0[(kk & 1) * 8 + e]
                                      : s1[(kk & 1) * 8 + e];
            pv[e] = exp2f(sv - mi);
          }
          // own pairs: a0=keys 4h+{0,1}, a1=4h+{2,3}, b0=8+4h+{0,1}, b1=...
          unsigned int a0 = cvtpk(pv[0], pv[1]);
          unsigned int a1 = cvtpk(pv[2], pv[3]);
          unsigned int b0 = cvtpk(pv[4], pv[5]);
          unsigned int b1 = cvtpk(pv[6], pv[7]);
          // swap32(a,b): a.hi <-> b.lo (low-key pair FIRST, HW-verified R12)
          swap32(a0, b0);
          swap32(a1, b1);
          union { unsigned int u[4]; bf16x8 v; } pf;
          pf.u[0] = a0; pf.u[1] = a1; pf.u[2] = b0; pf.u[3] = b1;

          bf16x8 vf0 = *(const bf16x8*)(Vb + q32 * 128 +
                                        ((32 * kk + 16 * h) ^ swb));
          bf16x8 vf1 = *(const bf16x8*)(Vb + (32 + q32) * 128 +
                                        ((32 * kk + 16 * h) ^ swb));
          acc0 = MFMA32(vf0, pf.v, acc0);
          acc1 = MFMA32(vf1, pf.v, acc1);
          z = MFMA32(ones.v, pf.v, z);   // row-sum on the matrix pipe
        }
        li += z[0];   // all rows of z are equal; z[0] = sum over 64 keys
      }

      // barrier: publishes prefetched tile (vmcnt drain) + buf-reuse guard
      __syncthreads();
      cur ^= 1;
    }

    // partial epilogue: o_norm (bf16) + s = mi + log2(li) per q-row.
    // acc: lane q = lane&31, d = (r&3)+8(r>>2)+4h (+32 for acc1)
    if (lane < 32) sbh[qw + lane] = (li > 0.f) ? (mi + log2f(li)) : NEG_INF;
    const float inv = (li > 0.f) ? 1.0f / li : 0.f;
    const size_t base = ((size_t)bh * T_SEQ + qw + q32) * DH;
#pragma unroll
    for (int dt = 0; dt < 2; ++dt) {
#pragma unroll
      for (int p4 = 0; p4 < 4; ++p4) {
        const float v0 = (dt ? acc1[4 * p4 + 0] : acc0[4 * p4 + 0]) * inv;
        const float v1 = (dt ? acc1[4 * p4 + 1] : acc0[4 * p4 + 1]) * inv;
        const float v2 = (dt ? acc1[4 * p4 + 2] : acc0[4 * p4 + 2]) * inv;
        const float v3 = (dt ? acc1[4 * p4 + 3] : acc0[4 * p4 + 3]) * inv;
        const int d0 = 32 * dt + 8 * p4 + 4 * h;
        *(unsigned int*)&obh[base + d0]     = cvtpk(v0, v1);
        *(unsigned int*)&obh[base + d0 + 2] = cvtpk(v2, v3);
      }
    }
  }
#undef STAGE
}

// ---------------- split-K merge (4 partials) ----------------
// y[(b*T+q)*512 + h*64 + d] = sum_i w_i * o_i, w_i = 2^(s_i - max) normalized.
// 256 threads = 32 rows x 8 dim-segments (8 bf16 = 16B each).
__global__ __launch_bounds__(256) void merge_kernel(
    const unsigned short* __restrict__ opart,
    const float* __restrict__ sb,
    unsigned short* __restrict__ yb) {
  const int t = threadIdx.x;
  const int r = blockIdx.x * 32 + (t >> 3);   // global (bh,q) row, 0..65535
  const int dseg = (t & 7) * 8;
  float s[NSPLIT];
#pragma unroll
  for (int i = 0; i < NSPLIT; ++i) s[i] = sb[(size_t)i * NROWS + r];
  const float S = fmaxf(fmaxf(s[0], s[1]), fmaxf(s[2], s[3]));
  float a[NSPLIT], wsum = 0.f;
#pragma unroll
  for (int i = 0; i < NSPLIT; ++i) { a[i] = exp2f(s[i] - S); wsum += a[i]; }
  const float inv = 1.0f / wsum;
  float acc[8] = {};
#pragma unroll
  for (int i = 0; i < NSPLIT; ++i) {
    const float ai = a[i] * inv;
    const uint4 u = *(const uint4*)&opart[(size_t)i * NROWS * DH +
                                          (size_t)r * DH + dseg];
    const unsigned int* pu = (const unsigned int*)&u;
#pragma unroll
    for (int j = 0; j < 4; ++j) {
      acc[2 * j]     += ai * __uint_as_float(pu[j] << 16);
      acc[2 * j + 1] += ai * __uint_as_float(pu[j] & 0xffff0000u);
    }
  }
  unsigned int ow[4];
#pragma unroll
  for (int j = 0; j < 4; ++j) ow[j] = pack_bf2(acc[2 * j], acc[2 * j + 1]);
  const int bh = r >> 12, q = r & 4095;
  const int bb = bh >> 3, hh = bh & 7;
  *(uint4*)&yb[((size_t)(bb * T_SEQ + q)) * 512 + hh * DH + dseg] = *(uint4*)ow;
}

// ---------------- launch ----------------
extern "C" void kernel_launch(void* const* d_in, const int* in_sizes, int n_in,
                              void* d_out, int out_size, void* d_ws, size_t ws_size,
                              hipStream_t stream) {
  const float* x     = (const float*)d_in[0];
  const float* w_qkv = (const float*)d_in[1];
  const float* b_qkv = (const float*)d_in[2];
  const float* w_out = (const float*)d_in[3];
  const float* b_out = (const float*)d_in[4];
  float* out = (float*)d_out;

  char* p = (char*)d_ws;
  unsigned short* xb    = (unsigned short*)p; p += (size_t)8192 * 512 * 2;
  unsigned short* wqkvT = (unsigned short*)p; p += (size_t)1536 * 512 * 2;
  unsigned short* woutT = (unsigned short*)p; p += (size_t)512 * 512 * 2;
  unsigned short* qbuf  = (unsigned short*)p; p += (size_t)16 * T_SEQ * DH * 2;
  unsigned short* kbuf  = (unsigned short*)p; p += (size_t)16 * T_SEQ * DH * 2;
  unsigned short* vtbuf = (unsigned short*)p; p += (size_t)16 * T_SEQ * DH * 2;
  unsigned short* ybuf  = (unsigned short*)p; p += (size_t)8192 * 512 * 2;
  unsigned short* opart = (unsigned short*)p; p += (size_t)NSPLIT * NROWS * DH * 2;
  float*          sbuf  = (float*)p;          p += (size_t)NSPLIT * NROWS * 4;

  // fused conversions (x, w_qkv^T, w_out^T) in one launch
  cvt_all_kernel<<<8192, 256, 0, stream>>>(x, w_qkv, w_out, xb, wqkvT, woutT);

  // QKV projection: M=8192, N=1536, K=512
  gemm_qkv<<<dim3(12, 64), 256, 0, stream>>>(xb, wqkvT, b_qkv,
                                             qbuf, kbuf, vtbuf, 512);
  // attention: 128-q superblocks, paired + 4-way split-K (1024 equal blocks)
  attn_kernel<<<dim3(16, 16, NSPLIT), 256, 0, stream>>>(qbuf, kbuf, vtbuf,
                                                        opart, sbuf);
  merge_kernel<<<NROWS / 32, 256, 0, stream>>>(opart, sbuf, ybuf);
  // output projection: M=8192, N=512, K=512 -- 64x128 tile, 512 blocks
  gemm_out<<<dim3(4, 128), 256, 0, stream>>>(ybuf, woutT, b_out, out, 512);
}